// Round 7
// baseline (513.265 us; speedup 1.0000x reference)
//
#include <hip/hip_runtime.h>
#include <hip/hip_bf16.h>
#include <cstdint>
#include <cstddef>

#define DEVI __device__ __forceinline__

static constexpr int SEQ = 2048;
static constexpr int DM  = 1024;
static constexpr int NH  = 16;
static constexpr int HD  = 64;
static constexpr int NTOK = 2 * SEQ;
static constexpr int NBUCKET = 257;

typedef __attribute__((ext_vector_type(8))) short bf16x8;
typedef __attribute__((ext_vector_type(4))) float f32x4;
#define MFMA16(a, b, c) __builtin_amdgcn_mfma_f32_16x16x32_bf16((a), (b), (c), 0, 0, 0)

DEVI float bf1(uint16_t u)  { return __uint_as_float(((uint32_t)u) << 16); }
DEVI uint16_t f2bf(float f) {
    uint32_t x = __float_as_uint(f);
    x += 0x7fffu + ((x >> 16) & 1u);   // RTNE
    return (uint16_t)(x >> 16);
}
DEVI bf16x8 ld_frag(const uint16_t* p) {
    union { uint4 u; bf16x8 f; } c;
    c.u = *(const uint4*)p;
    return c.f;
}
DEVI void gld16(const uint16_t* g, uint16_t* l) {
    __builtin_amdgcn_global_load_lds(
        (const __attribute__((address_space(1))) uint32_t*)g,
        (__attribute__((address_space(3))) uint32_t*)l, 16, 0, 0);
}

// ============================================================
__global__ void sniff_kernel(const uint16_t* __restrict__ x, int* __restrict__ flag)
{
    int bad = 0;
    for (int i = threadIdx.x; i < 512; i += 64) {
        const float v = bf1(x[i]);
        if (!(fabsf(v) < 64.0f)) bad = 1;
    }
    const unsigned long long m = __ballot(bad);
    if (threadIdx.x == 0) *flag = (m != 0ull) ? 1 : 0;
}

// ============================================================
__global__ __launch_bounds__(256)
void convert_kernel(const void* __restrict__ x, const void* __restrict__ Wq,
                    const void* __restrict__ Wk, const void* __restrict__ Wv,
                    const void* __restrict__ Wo, const void* __restrict__ bq,
                    const void* __restrict__ bk, const void* __restrict__ bv,
                    const void* __restrict__ bo, uint16_t* __restrict__ dst,
                    const int* __restrict__ flagp)
{
    const bool f32in = (*flagp != 0);
    const size_t M4 = 4194304, M1 = 1048576;
    const size_t e = ((size_t)blockIdx.x * 256 + threadIdx.x) * 8;
    const void* src; size_t off;
    if      (e < M4)                 { src = x;  off = e; }
    else if (e < M4 + M1)            { src = Wq; off = e - M4; }
    else if (e < M4 + 2*M1)          { src = Wk; off = e - M4 - M1; }
    else if (e < M4 + 3*M1)          { src = Wv; off = e - M4 - 2*M1; }
    else if (e < M4 + 4*M1)          { src = Wo; off = e - M4 - 3*M1; }
    else if (e < M4 + 4*M1 + 1024)   { src = bq; off = e - M4 - 4*M1; }
    else if (e < M4 + 4*M1 + 2048)   { src = bk; off = e - M4 - 4*M1 - 1024; }
    else if (e < M4 + 4*M1 + 3072)   { src = bv; off = e - M4 - 4*M1 - 2048; }
    else                             { src = bo; off = e - M4 - 4*M1 - 3072; }
    if (f32in) {
        const float4 a = *(const float4*)((const float*)src + off);
        const float4 b = *(const float4*)((const float*)src + off + 4);
        uint4 o;
        o.x = (uint32_t)f2bf(a.x) | ((uint32_t)f2bf(a.y) << 16);
        o.y = (uint32_t)f2bf(a.z) | ((uint32_t)f2bf(a.w) << 16);
        o.z = (uint32_t)f2bf(b.x) | ((uint32_t)f2bf(b.y) << 16);
        o.w = (uint32_t)f2bf(b.z) | ((uint32_t)f2bf(b.w) << 16);
        *(uint4*)(dst + e) = o;
    } else {
        *(uint4*)(dst + e) = *(const uint4*)((const uint16_t*)src + off);
    }
}

// ============================================================
// Fused QKV MFMA GEMM. Q output PRESCALED by 0.125.
// ============================================================
__global__ __launch_bounds__(256)
void gemm_qkv(const uint16_t* __restrict__ xc, const uint16_t* __restrict__ Wqkv,
              const uint16_t* __restrict__ bqkv,
              uint16_t* __restrict__ Qw, uint16_t* __restrict__ Kw,
              uint16_t* __restrict__ Vt)
{
    __shared__ uint16_t As[128 * 32];
    __shared__ uint16_t Bs[128 * 32];
    const int tid = threadIdx.x, bx = blockIdx.x;
    const int lane = tid & 63, wave = tid >> 6;
    const int ln = lane & 15, quad = lane >> 4;
    const int wm = (wave & 1) * 64, wn = (wave >> 1) * 64;

    const uint16_t *Ab, *Bb;
    int bm, bn, vor;
    if (bx < 512) {
        vor = 0; bm = (bx >> 4) * 128; bn = (bx & 15) * 128;
        Ab = xc + (size_t)bm * DM;  Bb = Wqkv + (size_t)bn * DM;
    } else {
        vor = 1; const int b2 = bx - 512; bm = (b2 >> 5) * 128; bn = (b2 & 31) * 128;
        Ab = Wqkv + (size_t)(2048 + bm) * DM;  Bb = xc + (size_t)bn * DM;
    }

    f32x4 acc[4][4];
    #pragma unroll
    for (int i = 0; i < 4; ++i)
        #pragma unroll
        for (int j = 0; j < 4; ++j) acc[i][j] = (f32x4){0.f, 0.f, 0.f, 0.f};

    const int s0 = tid, s1 = 256 + tid;
    const uint16_t* ga0 = Ab + (size_t)(s0 >> 2) * DM + (s0 & 3) * 8;
    const uint16_t* ga1 = Ab + (size_t)(s1 >> 2) * DM + (s1 & 3) * 8;
    const uint16_t* gb0 = Bb + (size_t)(s0 >> 2) * DM + (s0 & 3) * 8;
    const uint16_t* gb1 = Bb + (size_t)(s1 >> 2) * DM + (s1 & 3) * 8;

    for (int k0 = 0; k0 < DM; k0 += 32) {
        __syncthreads();
        gld16(ga0 + k0, &As[s0 * 8]);
        gld16(ga1 + k0, &As[s1 * 8]);
        gld16(gb0 + k0, &Bs[s0 * 8]);
        gld16(gb1 + k0, &Bs[s1 * 8]);
        __syncthreads();

        bf16x8 af[4], bfr[4];
        #pragma unroll
        for (int t = 0; t < 4; ++t) {
            af[t]  = ld_frag(&As[(wm + t * 16 + ln) * 32 + quad * 8]);
            bfr[t] = ld_frag(&Bs[(wn + t * 16 + ln) * 32 + quad * 8]);
        }
        #pragma unroll
        for (int ti = 0; ti < 4; ++ti)
            #pragma unroll
            for (int tj = 0; tj < 4; ++tj)
                acc[ti][tj] = MFMA16(af[ti], bfr[tj], acc[ti][tj]);
    }

    if (!vor) {
        #pragma unroll
        for (int tj = 0; tj < 4; ++tj) {
            const int c = bn + wn + tj * 16 + ln;
            const int mat = c >> 10, h = (c >> 6) & 15, hd = c & 63;
            uint16_t* dstp = mat ? Kw : Qw;
            const float scale = mat ? 1.0f : 0.125f;
            const float bb = bf1(bqkv[c]);
            #pragma unroll
            for (int ti = 0; ti < 4; ++ti)
                #pragma unroll
                for (int r = 0; r < 4; ++r) {
                    const int row = bm + wm + ti * 16 + quad * 4 + r;
                    const int b = row >> 11, s = row & 2047;
                    dstp[(((size_t)b * NH + h) * SEQ + s) * HD + hd] =
                        f2bf((acc[ti][tj][r] + bb) * scale);
                }
        }
    } else {
        #pragma unroll
        for (int ti = 0; ti < 4; ++ti)
            #pragma unroll
            for (int r = 0; r < 4; ++r) {
                const int f = bm + wm + ti * 16 + quad * 4 + r;
                const int h = f >> 6, hd = f & 63;
                const float bb = bf1(bqkv[2048 + f]);
                #pragma unroll
                for (int tj = 0; tj < 4; ++tj) {
                    const int t = bn + wn + tj * 16 + ln;
                    const int b = t >> 11, s = t & 2047;
                    Vt[(((size_t)b * NH + h) * HD + hd) * SEQ + s] = f2bf(acc[ti][tj][r] + bb);
                }
            }
    }
}

// ============================================================
__global__ __launch_bounds__(256)
void gemm_out(const uint16_t* __restrict__ Cw, const uint16_t* __restrict__ Woc,
              const uint16_t* __restrict__ boc, void* __restrict__ out,
              const int* __restrict__ flagp)
{
    __shared__ uint16_t As[128 * 32];
    __shared__ uint16_t Bs[128 * 32];
    const int tid = threadIdx.x, bx = blockIdx.x;
    const int lane = tid & 63, wave = tid >> 6;
    const int ln = lane & 15, quad = lane >> 4;
    const int wm = (wave & 1) * 64, wn = (wave >> 1) * 64;
    const int bm = (bx >> 3) * 128, bn = (bx & 7) * 128;
    const uint16_t* Ab = Cw + (size_t)bm * DM;
    const uint16_t* Bb = Woc + (size_t)bn * DM;

    f32x4 acc[4][4];
    #pragma unroll
    for (int i = 0; i < 4; ++i)
        #pragma unroll
        for (int j = 0; j < 4; ++j) acc[i][j] = (f32x4){0.f, 0.f, 0.f, 0.f};

    const int s0 = tid, s1 = 256 + tid;
    const uint16_t* ga0 = Ab + (size_t)(s0 >> 2) * DM + (s0 & 3) * 8;
    const uint16_t* ga1 = Ab + (size_t)(s1 >> 2) * DM + (s1 & 3) * 8;
    const uint16_t* gb0 = Bb + (size_t)(s0 >> 2) * DM + (s0 & 3) * 8;
    const uint16_t* gb1 = Bb + (size_t)(s1 >> 2) * DM + (s1 & 3) * 8;

    for (int k0 = 0; k0 < DM; k0 += 32) {
        __syncthreads();
        gld16(ga0 + k0, &As[s0 * 8]);
        gld16(ga1 + k0, &As[s1 * 8]);
        gld16(gb0 + k0, &Bs[s0 * 8]);
        gld16(gb1 + k0, &Bs[s1 * 8]);
        __syncthreads();

        bf16x8 af[4], bfr[4];
        #pragma unroll
        for (int t = 0; t < 4; ++t) {
            af[t]  = ld_frag(&As[(wm + t * 16 + ln) * 32 + quad * 8]);
            bfr[t] = ld_frag(&Bs[(wn + t * 16 + ln) * 32 + quad * 8]);
        }
        #pragma unroll
        for (int ti = 0; ti < 4; ++ti)
            #pragma unroll
            for (int tj = 0; tj < 4; ++tj)
                acc[ti][tj] = MFMA16(af[ti], bfr[tj], acc[ti][tj]);
    }

    const bool f32o = (*flagp != 0);
    #pragma unroll
    for (int tj = 0; tj < 4; ++tj) {
        const int c = bn + wn + tj * 16 + ln;
        const float bb = bf1(boc[c]);
        #pragma unroll
        for (int ti = 0; ti < 4; ++ti)
            #pragma unroll
            for (int r = 0; r < 4; ++r) {
                const int row = bm + wm + ti * 16 + quad * 4 + r;
                const float v = acc[ti][tj][r] + bb;
                if (f32o) ((float*)out)[(size_t)row * DM + c] = v;
                else      ((uint16_t*)out)[(size_t)row * DM + c] = f2bf(v);
            }
    }
}

// ============================================================
// Flash-style MFMA attention v5.
// v4 + two fixes:
//  * __launch_bounds__(256,3): VGPR cap ~170 (was 128 via the ",2" hint ->
//    scratch spills = 145 MB of HBM writes). LDS caps occupancy at 3
//    blocks/CU anyway, so nothing is lost.
//  * Pl row stride 136 (no XOR): b64 P-writes land 4 slots/bank (= the
//    wave64-b64 floor, conflict-free-equivalent); b128 pf reads land
//    8 slots/bank (= b128 floor). Kills the 5.2M bank-conflict cycles.
// ============================================================
__global__ __launch_bounds__(256, 3)
void attn_mfma(const uint16_t* __restrict__ Q, const uint16_t* __restrict__ K,
               const uint16_t* __restrict__ Vt, const void* __restrict__ rel,
               uint16_t* __restrict__ ctx, const int* __restrict__ flagp)
{
    __shared__ alignas(16) uint16_t Ks[128 * 64];    // [key][d], XOR-swizzled
    __shared__ alignas(16) uint16_t Vls[64 * 128];   // [d][key], XOR-swizzled
    __shared__ alignas(16) uint16_t Pl[4][16 * 136]; // per-wave P [q][key], padded
    __shared__ float bias_s[NBUCKET];

    const bool f32in = (*flagp != 0);
    const int tid = threadIdx.x, wave = tid >> 6, lane = tid & 63;
    const int ln = lane & 15, quad = lane >> 4;

    const int blk = blockIdx.x;
    const int bh = (blk & 7) * 4 + ((blk >> 3) & 3);   // 4 bh per XCD
    const int qt = blk >> 5;                            // 16 q-tiles, same XCD
    const int b = bh >> 4, h = bh & 15;
    const int q0 = qt * 128;

    for (int i = tid; i < NBUCKET; i += 256)
        bias_s[i] = f32in ? ((const float*)rel)[i * NH + h]
                          : bf1(((const uint16_t*)rel)[i * NH + h]);
    __syncthreads();
    const float bneg = bias_s[0], bpos = bias_s[256];

    // Q B-frags: lane ln = q-row, k = quad*8+j
    bf16x8 qf[2][2];
    #pragma unroll
    for (int mt = 0; mt < 2; ++mt) {
        const uint16_t* qp = Q + ((size_t)bh * SEQ + q0 + wave * 32 + mt * 16 + ln) * HD;
        qf[mt][0] = ld_frag(qp + quad * 8);
        qf[mt][1] = ld_frag(qp + 32 + quad * 8);
    }

    f32x4 o[2][4];
    float lacc[2] = {0.f, 0.f};
    #pragma unroll
    for (int mt = 0; mt < 2; ++mt)
        #pragma unroll
        for (int dt = 0; dt < 4; ++dt) o[mt][dt] = (f32x4){0.f, 0.f, 0.f, 0.f};

    const uint16_t* Kb  = K  + (size_t)bh * SEQ * HD;
    const uint16_t* Vtb = Vt + (size_t)bh * HD * SEQ;
    const int swz = ln & 7;
    uint16_t* myP = Pl[wave];

    for (int k0 = 0; k0 < SEQ; k0 += 128) {
        __syncthreads();
        #pragma unroll
        for (int it = 0; it < 4; ++it) {   // K tile: 128 rows x 128 B
            const int s = it * 256 + tid;
            const int row = s >> 3, p = s & 7, c = p ^ (row & 7);
            gld16(Kb + (size_t)(k0 + row) * HD + c * 8, &Ks[s * 8]);
        }
        #pragma unroll
        for (int it = 0; it < 4; ++it) {   // V tile: 64 rows x 256 B
            const int s = it * 256 + tid;
            const int row = s >> 4, p = s & 15, c = p ^ (row & 7);
            gld16(Vtb + (size_t)row * SEQ + k0 + c * 8, &Vls[s * 8]);
        }
        __syncthreads();

        const int mode = (k0 >= q0 + 256) ? 0 : ((k0 + 256 <= q0) ? 2 : 1);
        const float bcst = ((mode == 0) ? bneg : bpos) - 8.0f;

        #pragma unroll
        for (int mt = 0; mt < 2; ++mt) {
            // ---- S^T = K·Q^T; exp; P -> LDS (one b64 per 16-key tile) ----
            #pragma unroll
            for (int nt = 0; nt < 8; ++nt) {
                const int krow = (nt * 16 + ln) * 64;
                const bf16x8 kf0 = ld_frag(&Ks[krow + ((0 + quad) ^ swz) * 8]);
                const bf16x8 kf1 = ld_frag(&Ks[krow + ((4 + quad) ^ swz) * 8]);
                f32x4 s4 = (f32x4){0.f, 0.f, 0.f, 0.f};
                s4 = MFMA16(kf0, qf[mt][0], s4);   // A=K(rows=keys), B=Q(cols=q)
                s4 = MFMA16(kf1, qf[mt][1], s4);
                uint32_t pb[4];
                #pragma unroll
                for (int r = 0; r < 4; ++r) {
                    float sv;
                    if (mode != 1) {
                        sv = s4[r] + bcst;
                    } else {
                        const int kk = k0 + nt * 16 + quad * 4 + r;
                        const int qq = q0 + wave * 32 + mt * 16 + ln;
                        int dd = qq - kk;
                        dd = min(128, max(-128, dd)) + 128;
                        sv = s4[r] + bias_s[dd] - 8.0f;
                    }
                    pb[r] = __float_as_uint(__expf(sv)) & 0xffff0000u;
                    lacc[mt] += __uint_as_float(pb[r]);   // l matches bf16 P
                }
                const uint2 dw = {(pb[0] >> 16) | pb[1], (pb[2] >> 16) | pb[3]};
                *(uint2*)&myP[ln * 136 + nt * 16 + quad * 4] = dw;
            }
            // ---- PV for this subtile (consumes myP before mt+1 overwrites) ----
            bf16x8 pf[4];
            #pragma unroll
            for (int kc = 0; kc < 4; ++kc)
                pf[kc] = ld_frag(&myP[ln * 136 + kc * 32 + quad * 8]);
            #pragma unroll
            for (int dt = 0; dt < 4; ++dt) {
                const int vrow = (dt * 16 + ln) * 128;
                #pragma unroll
                for (int kc = 0; kc < 4; ++kc) {
                    const bf16x8 vf = ld_frag(&Vls[vrow + ((kc * 4 + quad) ^ swz) * 8]);
                    o[mt][dt] = MFMA16(pf[kc], vf, o[mt][dt]);
                }
            }
        }
    }

    // ---- epilogue: reduce l over quads, redistribute, divide, store ----
    #pragma unroll
    for (int mt = 0; mt < 2; ++mt) {
        float lr = lacc[mt];
        lr += __shfl_xor(lr, 16);
        lr += __shfl_xor(lr, 32);
        const float linv = 1.0f / lr;      // valid for q-row = ln
        #pragma unroll
        for (int r = 0; r < 4; ++r) {
            const float inv_r = __shfl(linv, quad * 4 + r);  // l for q=quad*4+r
            const int qq = q0 + wave * 32 + mt * 16 + quad * 4 + r;
            #pragma unroll
            for (int dt = 0; dt < 4; ++dt) {
                const float v = o[mt][dt][r] * inv_r;
                ctx[(((size_t)b * SEQ + qq) * NH + h) * HD + dt * 16 + ln] = f2bf(v);
            }
        }
    }
}

// ============================================================
extern "C" void kernel_launch(void* const* d_in, const int* in_sizes, int n_in,
                              void* d_out, int out_size, void* d_ws, size_t ws_size,
                              hipStream_t stream)
{
    const void* x   = d_in[0];
    const void* Wq  = d_in[1];
    const void* bq  = d_in[2];
    const void* Wk  = d_in[3];
    const void* bk  = d_in[4];
    const void* Wv  = d_in[5];
    const void* bv  = d_in[6];
    const void* Wo  = d_in[7];
    const void* bo  = d_in[8];
    const void* rel = d_in[9];

    const size_t M4 = 4194304, M1 = 1048576;
    uint16_t* ws16 = (uint16_t*)d_ws;
    uint16_t* xc   = ws16;                    // 4M; reused as Cw after QKV GEMM
    uint16_t* Wqkv = ws16 + M4;               // 3M  [Wq;Wk;Wv]
    uint16_t* Woc  = ws16 + M4 + 3 * M1;      // 1M
    uint16_t* bqkv = ws16 + M4 + 4 * M1;      // 3072 [bq;bk;bv]
    uint16_t* boc  = bqkv + 3072;             // 1024
    uint16_t* Qw   = ws16 + M4 + 4 * M1 + 8192;
    uint16_t* Kw   = Qw + M4;
    uint16_t* Vt   = Kw + M4;
    int* flag = (int*)(Vt + M4);
    uint16_t* Cw = xc;   // overlay: xc dead after gemm_qkv

    sniff_kernel<<<1, 64, 0, stream>>>((const uint16_t*)x, flag);
    convert_kernel<<<4098, 256, 0, stream>>>(x, Wq, Wk, Wv, Wo, bq, bk, bv, bo,
                                             ws16, flag);
    gemm_qkv<<<768, 256, 0, stream>>>(xc, Wqkv, bqkv, Qw, Kw, Vt);
    attn_mfma<<<512, 256, 0, stream>>>(Qw, Kw, Vt, rel, Cw, flag);
    gemm_out<<<256, 256, 0, stream>>>(Cw, Woc, boc, d_out, flag);
}

// Round 8
// 307.904 us; speedup vs baseline: 1.6670x; 1.6670x over previous
//
#include <hip/hip_runtime.h>
#include <hip/hip_bf16.h>
#include <cstdint>
#include <cstddef>

#define DEVI __device__ __forceinline__

static constexpr int SEQ = 2048;
static constexpr int DM  = 1024;
static constexpr int NH  = 16;
static constexpr int HD  = 64;
static constexpr int NTOK = 2 * SEQ;
static constexpr int NBUCKET = 257;

typedef __attribute__((ext_vector_type(8))) short bf16x8;
typedef __attribute__((ext_vector_type(4))) float f32x4;
#define MFMA16(a, b, c) __builtin_amdgcn_mfma_f32_16x16x32_bf16((a), (b), (c), 0, 0, 0)

DEVI float bf1(uint16_t u)  { return __uint_as_float(((uint32_t)u) << 16); }
DEVI uint16_t f2bf(float f) {
    uint32_t x = __float_as_uint(f);
    x += 0x7fffu + ((x >> 16) & 1u);   // RTNE
    return (uint16_t)(x >> 16);
}
DEVI bf16x8 ld_frag(const uint16_t* p) {
    union { uint4 u; bf16x8 f; } c;
    c.u = *(const uint4*)p;
    return c.f;
}
DEVI void gld16(const uint16_t* g, uint16_t* l) {
    __builtin_amdgcn_global_load_lds(
        (const __attribute__((address_space(1))) uint32_t*)g,
        (__attribute__((address_space(3))) uint32_t*)l, 16, 0, 0);
}

// ============================================================
__global__ void sniff_kernel(const uint16_t* __restrict__ x, int* __restrict__ flag)
{
    int bad = 0;
    for (int i = threadIdx.x; i < 512; i += 64) {
        const float v = bf1(x[i]);
        if (!(fabsf(v) < 64.0f)) bad = 1;
    }
    const unsigned long long m = __ballot(bad);
    if (threadIdx.x == 0) *flag = (m != 0ull) ? 1 : 0;
}

// ============================================================
__global__ __launch_bounds__(256)
void convert_kernel(const void* __restrict__ x, const void* __restrict__ Wq,
                    const void* __restrict__ Wk, const void* __restrict__ Wv,
                    const void* __restrict__ Wo, const void* __restrict__ bq,
                    const void* __restrict__ bk, const void* __restrict__ bv,
                    const void* __restrict__ bo, uint16_t* __restrict__ dst,
                    const int* __restrict__ flagp)
{
    const bool f32in = (*flagp != 0);
    const size_t M4 = 4194304, M1 = 1048576;
    const size_t e = ((size_t)blockIdx.x * 256 + threadIdx.x) * 8;
    const void* src; size_t off;
    if      (e < M4)                 { src = x;  off = e; }
    else if (e < M4 + M1)            { src = Wq; off = e - M4; }
    else if (e < M4 + 2*M1)          { src = Wk; off = e - M4 - M1; }
    else if (e < M4 + 3*M1)          { src = Wv; off = e - M4 - 2*M1; }
    else if (e < M4 + 4*M1)          { src = Wo; off = e - M4 - 3*M1; }
    else if (e < M4 + 4*M1 + 1024)   { src = bq; off = e - M4 - 4*M1; }
    else if (e < M4 + 4*M1 + 2048)   { src = bk; off = e - M4 - 4*M1 - 1024; }
    else if (e < M4 + 4*M1 + 3072)   { src = bv; off = e - M4 - 4*M1 - 2048; }
    else                             { src = bo; off = e - M4 - 4*M1 - 3072; }
    if (f32in) {
        const float4 a = *(const float4*)((const float*)src + off);
        const float4 b = *(const float4*)((const float*)src + off + 4);
        uint4 o;
        o.x = (uint32_t)f2bf(a.x) | ((uint32_t)f2bf(a.y) << 16);
        o.y = (uint32_t)f2bf(a.z) | ((uint32_t)f2bf(a.w) << 16);
        o.z = (uint32_t)f2bf(b.x) | ((uint32_t)f2bf(b.y) << 16);
        o.w = (uint32_t)f2bf(b.z) | ((uint32_t)f2bf(b.w) << 16);
        *(uint4*)(dst + e) = o;
    } else {
        *(uint4*)(dst + e) = *(const uint4*)((const uint16_t*)src + off);
    }
}

// ============================================================
// Fused QKV MFMA GEMM. Q output PRESCALED by 0.125.
// ============================================================
__global__ __launch_bounds__(256)
void gemm_qkv(const uint16_t* __restrict__ xc, const uint16_t* __restrict__ Wqkv,
              const uint16_t* __restrict__ bqkv,
              uint16_t* __restrict__ Qw, uint16_t* __restrict__ Kw,
              uint16_t* __restrict__ Vt)
{
    __shared__ uint16_t As[128 * 32];
    __shared__ uint16_t Bs[128 * 32];
    const int tid = threadIdx.x, bx = blockIdx.x;
    const int lane = tid & 63, wave = tid >> 6;
    const int ln = lane & 15, quad = lane >> 4;
    const int wm = (wave & 1) * 64, wn = (wave >> 1) * 64;

    const uint16_t *Ab, *Bb;
    int bm, bn, vor;
    if (bx < 512) {
        vor = 0; bm = (bx >> 4) * 128; bn = (bx & 15) * 128;
        Ab = xc + (size_t)bm * DM;  Bb = Wqkv + (size_t)bn * DM;
    } else {
        vor = 1; const int b2 = bx - 512; bm = (b2 >> 5) * 128; bn = (b2 & 31) * 128;
        Ab = Wqkv + (size_t)(2048 + bm) * DM;  Bb = xc + (size_t)bn * DM;
    }

    f32x4 acc[4][4];
    #pragma unroll
    for (int i = 0; i < 4; ++i)
        #pragma unroll
        for (int j = 0; j < 4; ++j) acc[i][j] = (f32x4){0.f, 0.f, 0.f, 0.f};

    const int s0 = tid, s1 = 256 + tid;
    const uint16_t* ga0 = Ab + (size_t)(s0 >> 2) * DM + (s0 & 3) * 8;
    const uint16_t* ga1 = Ab + (size_t)(s1 >> 2) * DM + (s1 & 3) * 8;
    const uint16_t* gb0 = Bb + (size_t)(s0 >> 2) * DM + (s0 & 3) * 8;
    const uint16_t* gb1 = Bb + (size_t)(s1 >> 2) * DM + (s1 & 3) * 8;

    for (int k0 = 0; k0 < DM; k0 += 32) {
        __syncthreads();
        gld16(ga0 + k0, &As[s0 * 8]);
        gld16(ga1 + k0, &As[s1 * 8]);
        gld16(gb0 + k0, &Bs[s0 * 8]);
        gld16(gb1 + k0, &Bs[s1 * 8]);
        __syncthreads();

        bf16x8 af[4], bfr[4];
        #pragma unroll
        for (int t = 0; t < 4; ++t) {
            af[t]  = ld_frag(&As[(wm + t * 16 + ln) * 32 + quad * 8]);
            bfr[t] = ld_frag(&Bs[(wn + t * 16 + ln) * 32 + quad * 8]);
        }
        #pragma unroll
        for (int ti = 0; ti < 4; ++ti)
            #pragma unroll
            for (int tj = 0; tj < 4; ++tj)
                acc[ti][tj] = MFMA16(af[ti], bfr[tj], acc[ti][tj]);
    }

    if (!vor) {
        #pragma unroll
        for (int tj = 0; tj < 4; ++tj) {
            const int c = bn + wn + tj * 16 + ln;
            const int mat = c >> 10, h = (c >> 6) & 15, hd = c & 63;
            uint16_t* dstp = mat ? Kw : Qw;
            const float scale = mat ? 1.0f : 0.125f;
            const float bb = bf1(bqkv[c]);
            #pragma unroll
            for (int ti = 0; ti < 4; ++ti)
                #pragma unroll
                for (int r = 0; r < 4; ++r) {
                    const int row = bm + wm + ti * 16 + quad * 4 + r;
                    const int b = row >> 11, s = row & 2047;
                    dstp[(((size_t)b * NH + h) * SEQ + s) * HD + hd] =
                        f2bf((acc[ti][tj][r] + bb) * scale);
                }
        }
    } else {
        #pragma unroll
        for (int ti = 0; ti < 4; ++ti)
            #pragma unroll
            for (int r = 0; r < 4; ++r) {
                const int f = bm + wm + ti * 16 + quad * 4 + r;
                const int h = f >> 6, hd = f & 63;
                const float bb = bf1(bqkv[2048 + f]);
                #pragma unroll
                for (int tj = 0; tj < 4; ++tj) {
                    const int t = bn + wn + tj * 16 + ln;
                    const int b = t >> 11, s = t & 2047;
                    Vt[(((size_t)b * NH + h) * HD + hd) * SEQ + s] = f2bf(acc[ti][tj][r] + bb);
                }
            }
    }
}

// ============================================================
__global__ __launch_bounds__(256)
void gemm_out(const uint16_t* __restrict__ Cw, const uint16_t* __restrict__ Woc,
              const uint16_t* __restrict__ boc, void* __restrict__ out,
              const int* __restrict__ flagp)
{
    __shared__ uint16_t As[128 * 32];
    __shared__ uint16_t Bs[128 * 32];
    const int tid = threadIdx.x, bx = blockIdx.x;
    const int lane = tid & 63, wave = tid >> 6;
    const int ln = lane & 15, quad = lane >> 4;
    const int wm = (wave & 1) * 64, wn = (wave >> 1) * 64;
    const int bm = (bx >> 3) * 128, bn = (bx & 7) * 128;
    const uint16_t* Ab = Cw + (size_t)bm * DM;
    const uint16_t* Bb = Woc + (size_t)bn * DM;

    f32x4 acc[4][4];
    #pragma unroll
    for (int i = 0; i < 4; ++i)
        #pragma unroll
        for (int j = 0; j < 4; ++j) acc[i][j] = (f32x4){0.f, 0.f, 0.f, 0.f};

    const int s0 = tid, s1 = 256 + tid;
    const uint16_t* ga0 = Ab + (size_t)(s0 >> 2) * DM + (s0 & 3) * 8;
    const uint16_t* ga1 = Ab + (size_t)(s1 >> 2) * DM + (s1 & 3) * 8;
    const uint16_t* gb0 = Bb + (size_t)(s0 >> 2) * DM + (s0 & 3) * 8;
    const uint16_t* gb1 = Bb + (size_t)(s1 >> 2) * DM + (s1 & 3) * 8;

    for (int k0 = 0; k0 < DM; k0 += 32) {
        __syncthreads();
        gld16(ga0 + k0, &As[s0 * 8]);
        gld16(ga1 + k0, &As[s1 * 8]);
        gld16(gb0 + k0, &Bs[s0 * 8]);
        gld16(gb1 + k0, &Bs[s1 * 8]);
        __syncthreads();

        bf16x8 af[4], bfr[4];
        #pragma unroll
        for (int t = 0; t < 4; ++t) {
            af[t]  = ld_frag(&As[(wm + t * 16 + ln) * 32 + quad * 8]);
            bfr[t] = ld_frag(&Bs[(wn + t * 16 + ln) * 32 + quad * 8]);
        }
        #pragma unroll
        for (int ti = 0; ti < 4; ++ti)
            #pragma unroll
            for (int tj = 0; tj < 4; ++tj)
                acc[ti][tj] = MFMA16(af[ti], bfr[tj], acc[ti][tj]);
    }

    const bool f32o = (*flagp != 0);
    #pragma unroll
    for (int tj = 0; tj < 4; ++tj) {
        const int c = bn + wn + tj * 16 + ln;
        const float bb = bf1(boc[c]);
        #pragma unroll
        for (int ti = 0; ti < 4; ++ti)
            #pragma unroll
            for (int r = 0; r < 4; ++r) {
                const int row = bm + wm + ti * 16 + quad * 4 + r;
                const float v = acc[ti][tj][r] + bb;
                if (f32o) ((float*)out)[(size_t)row * DM + c] = v;
                else      ((uint16_t*)out)[(size_t)row * DM + c] = f2bf(v);
            }
    }
}

// ============================================================
// Flash-style MFMA attention v6.
// = v4/v5 structure with:
//  * PLAIN __launch_bounds__(256): no waves-per-EU constraint, so the
//    allocator sizes registers to real pressure (~140) and never spills.
//    (The ",2"/",3" hints split the unified VGPR/AGPR budget and forced
//    84-128 arch VGPRs -> 145-895 MB scratch traffic. r6/r7 evidence.)
//  * Pl row stride 136: b64 P-writes at the 4-slot/bank floor, b128 reads
//    at the 8-slot floor.
//  * v_perm_b32 packs the two bf16 P halves (1 instr per pair).
// ============================================================
__global__ __launch_bounds__(256)
void attn_mfma(const uint16_t* __restrict__ Q, const uint16_t* __restrict__ K,
               const uint16_t* __restrict__ Vt, const void* __restrict__ rel,
               uint16_t* __restrict__ ctx, const int* __restrict__ flagp)
{
    __shared__ alignas(16) uint16_t Ks[128 * 64];    // [key][d], XOR-swizzled
    __shared__ alignas(16) uint16_t Vls[64 * 128];   // [d][key], XOR-swizzled
    __shared__ alignas(16) uint16_t Pl[4][16 * 136]; // per-wave P [q][key], padded
    __shared__ float bias_s[NBUCKET];

    const bool f32in = (*flagp != 0);
    const int tid = threadIdx.x, wave = tid >> 6, lane = tid & 63;
    const int ln = lane & 15, quad = lane >> 4;

    const int blk = blockIdx.x;
    const int bh = (blk & 7) * 4 + ((blk >> 3) & 3);   // 4 bh per XCD
    const int qt = blk >> 5;                            // 16 q-tiles, same XCD
    const int b = bh >> 4, h = bh & 15;
    const int q0 = qt * 128;

    for (int i = tid; i < NBUCKET; i += 256)
        bias_s[i] = f32in ? ((const float*)rel)[i * NH + h]
                          : bf1(((const uint16_t*)rel)[i * NH + h]);
    __syncthreads();
    const float bneg = bias_s[0], bpos = bias_s[256];

    // Q B-frags: lane ln = q-row, k = quad*8+j
    bf16x8 qf[2][2];
    #pragma unroll
    for (int mt = 0; mt < 2; ++mt) {
        const uint16_t* qp = Q + ((size_t)bh * SEQ + q0 + wave * 32 + mt * 16 + ln) * HD;
        qf[mt][0] = ld_frag(qp + quad * 8);
        qf[mt][1] = ld_frag(qp + 32 + quad * 8);
    }

    f32x4 o[2][4];
    float lacc[2] = {0.f, 0.f};
    #pragma unroll
    for (int mt = 0; mt < 2; ++mt)
        #pragma unroll
        for (int dt = 0; dt < 4; ++dt) o[mt][dt] = (f32x4){0.f, 0.f, 0.f, 0.f};

    const uint16_t* Kb  = K  + (size_t)bh * SEQ * HD;
    const uint16_t* Vtb = Vt + (size_t)bh * HD * SEQ;
    const int swz = ln & 7;
    uint16_t* myP = Pl[wave];

    for (int k0 = 0; k0 < SEQ; k0 += 128) {
        __syncthreads();
        #pragma unroll
        for (int it = 0; it < 4; ++it) {   // K tile: 128 rows x 128 B
            const int s = it * 256 + tid;
            const int row = s >> 3, p = s & 7, c = p ^ (row & 7);
            gld16(Kb + (size_t)(k0 + row) * HD + c * 8, &Ks[s * 8]);
        }
        #pragma unroll
        for (int it = 0; it < 4; ++it) {   // V tile: 64 rows x 256 B
            const int s = it * 256 + tid;
            const int row = s >> 4, p = s & 15, c = p ^ (row & 7);
            gld16(Vtb + (size_t)row * SEQ + k0 + c * 8, &Vls[s * 8]);
        }
        __syncthreads();

        const int mode = (k0 >= q0 + 256) ? 0 : ((k0 + 256 <= q0) ? 2 : 1);
        const float bcst = ((mode == 0) ? bneg : bpos) - 8.0f;

        #pragma unroll
        for (int mt = 0; mt < 2; ++mt) {
            // ---- S^T = K·Q^T; exp; P -> LDS (one b64 per 16-key tile) ----
            #pragma unroll
            for (int nt = 0; nt < 8; ++nt) {
                const int krow = (nt * 16 + ln) * 64;
                const bf16x8 kf0 = ld_frag(&Ks[krow + ((0 + quad) ^ swz) * 8]);
                const bf16x8 kf1 = ld_frag(&Ks[krow + ((4 + quad) ^ swz) * 8]);
                f32x4 s4 = (f32x4){0.f, 0.f, 0.f, 0.f};
                s4 = MFMA16(kf0, qf[mt][0], s4);   // A=K(rows=keys), B=Q(cols=q)
                s4 = MFMA16(kf1, qf[mt][1], s4);
                uint32_t pb[4];
                #pragma unroll
                for (int r = 0; r < 4; ++r) {
                    float sv;
                    if (mode != 1) {
                        sv = s4[r] + bcst;
                    } else {
                        const int kk = k0 + nt * 16 + quad * 4 + r;
                        const int qq = q0 + wave * 32 + mt * 16 + ln;
                        int dd = qq - kk;
                        dd = min(128, max(-128, dd)) + 128;
                        sv = s4[r] + bias_s[dd] - 8.0f;
                    }
                    pb[r] = __float_as_uint(__expf(sv)) & 0xffff0000u;
                    lacc[mt] += __uint_as_float(pb[r]);   // l matches bf16 P
                }
                // pack [hi16(pb0)|hi16(pb1)], [hi16(pb2)|hi16(pb3)] in 1 instr each
                const uint2 dw = {__builtin_amdgcn_perm(pb[1], pb[0], 0x07060302u),
                                  __builtin_amdgcn_perm(pb[3], pb[2], 0x07060302u)};
                *(uint2*)&myP[ln * 136 + nt * 16 + quad * 4] = dw;
            }
            // ---- PV for this subtile (consumes myP before mt+1 overwrites) ----
            bf16x8 pf[4];
            #pragma unroll
            for (int kc = 0; kc < 4; ++kc)
                pf[kc] = ld_frag(&myP[ln * 136 + kc * 32 + quad * 8]);
            #pragma unroll
            for (int dt = 0; dt < 4; ++dt) {
                const int vrow = (dt * 16 + ln) * 128;
                #pragma unroll
                for (int kc = 0; kc < 4; ++kc) {
                    const bf16x8 vf = ld_frag(&Vls[vrow + ((kc * 4 + quad) ^ swz) * 8]);
                    o[mt][dt] = MFMA16(pf[kc], vf, o[mt][dt]);
                }
            }
        }
    }

    // ---- epilogue: reduce l over quads, redistribute, divide, store ----
    #pragma unroll
    for (int mt = 0; mt < 2; ++mt) {
        float lr = lacc[mt];
        lr += __shfl_xor(lr, 16);
        lr += __shfl_xor(lr, 32);
        const float linv = 1.0f / lr;      // valid for q-row = ln
        #pragma unroll
        for (int r = 0; r < 4; ++r) {
            const float inv_r = __shfl(linv, quad * 4 + r);  // l for q=quad*4+r
            const int qq = q0 + wave * 32 + mt * 16 + quad * 4 + r;
            #pragma unroll
            for (int dt = 0; dt < 4; ++dt) {
                const float v = o[mt][dt][r] * inv_r;
                ctx[(((size_t)b * SEQ + qq) * NH + h) * HD + dt * 16 + ln] = f2bf(v);
            }
        }
    }
}

// ============================================================
extern "C" void kernel_launch(void* const* d_in, const int* in_sizes, int n_in,
                              void* d_out, int out_size, void* d_ws, size_t ws_size,
                              hipStream_t stream)
{
    const void* x   = d_in[0];
    const void* Wq  = d_in[1];
    const void* bq  = d_in[2];
    const void* Wk  = d_in[3];
    const void* bk  = d_in[4];
    const void* Wv  = d_in[5];
    const void* bv  = d_in[6];
    const void* Wo  = d_in[7];
    const void* bo  = d_in[8];
    const void* rel = d_in[9];

    const size_t M4 = 4194304, M1 = 1048576;
    uint16_t* ws16 = (uint16_t*)d_ws;
    uint16_t* xc   = ws16;                    // 4M; reused as Cw after QKV GEMM
    uint16_t* Wqkv = ws16 + M4;               // 3M  [Wq;Wk;Wv]
    uint16_t* Woc  = ws16 + M4 + 3 * M1;      // 1M
    uint16_t* bqkv = ws16 + M4 + 4 * M1;      // 3072 [bq;bk;bv]
    uint16_t* boc  = bqkv + 3072;             // 1024
    uint16_t* Qw   = ws16 + M4 + 4 * M1 + 8192;
    uint16_t* Kw   = Qw + M4;
    uint16_t* Vt   = Kw + M4;
    int* flag = (int*)(Vt + M4);
    uint16_t* Cw = xc;   // overlay: xc dead after gemm_qkv

    sniff_kernel<<<1, 64, 0, stream>>>((const uint16_t*)x, flag);
    convert_kernel<<<4098, 256, 0, stream>>>(x, Wq, Wk, Wv, Wo, bq, bk, bv, bo,
                                             ws16, flag);
    gemm_qkv<<<768, 256, 0, stream>>>(xc, Wqkv, bqkv, Qw, Kw, Vt);
    attn_mfma<<<512, 256, 0, stream>>>(Qw, Kw, Vt, rel, Cw, flag);
    gemm_out<<<256, 256, 0, stream>>>(Cw, Woc, boc, d_out, flag);
}

// Round 9
// 257.579 us; speedup vs baseline: 1.9927x; 1.1954x over previous
//
#include <hip/hip_runtime.h>
#include <hip/hip_bf16.h>
#include <cstdint>
#include <cstddef>

#define DEVI __device__ __forceinline__

static constexpr int SEQ = 2048;
static constexpr int DM  = 1024;
static constexpr int NH  = 16;
static constexpr int HD  = 64;
static constexpr int NTOK = 2 * SEQ;
static constexpr int NBUCKET = 257;

typedef __attribute__((ext_vector_type(8))) short bf16x8;
typedef __attribute__((ext_vector_type(4))) float f32x4;
#define MFMA16(a, b, c) __builtin_amdgcn_mfma_f32_16x16x32_bf16((a), (b), (c), 0, 0, 0)

DEVI float bf1(uint16_t u)  { return __uint_as_float(((uint32_t)u) << 16); }
DEVI uint16_t f2bf(float f) {
    uint32_t x = __float_as_uint(f);
    x += 0x7fffu + ((x >> 16) & 1u);   // RTNE
    return (uint16_t)(x >> 16);
}
DEVI bf16x8 ld_frag(const uint16_t* p) {
    union { uint4 u; bf16x8 f; } c;
    c.u = *(const uint4*)p;
    return c.f;
}
DEVI void gld16(const uint16_t* g, uint16_t* l) {
    __builtin_amdgcn_global_load_lds(
        (const __attribute__((address_space(1))) uint32_t*)g,
        (__attribute__((address_space(3))) uint32_t*)l, 16, 0, 0);
}

// ============================================================
__global__ void sniff_kernel(const uint16_t* __restrict__ x, int* __restrict__ flag)
{
    int bad = 0;
    for (int i = threadIdx.x; i < 512; i += 64) {
        const float v = bf1(x[i]);
        if (!(fabsf(v) < 64.0f)) bad = 1;
    }
    const unsigned long long m = __ballot(bad);
    if (threadIdx.x == 0) *flag = (m != 0ull) ? 1 : 0;
}

// ============================================================
__global__ __launch_bounds__(256)
void convert_kernel(const void* __restrict__ x, const void* __restrict__ Wq,
                    const void* __restrict__ Wk, const void* __restrict__ Wv,
                    const void* __restrict__ Wo, const void* __restrict__ bq,
                    const void* __restrict__ bk, const void* __restrict__ bv,
                    const void* __restrict__ bo, uint16_t* __restrict__ dst,
                    const int* __restrict__ flagp)
{
    const bool f32in = (*flagp != 0);
    const size_t M4 = 4194304, M1 = 1048576;
    const size_t e = ((size_t)blockIdx.x * 256 + threadIdx.x) * 8;
    const void* src; size_t off;
    if      (e < M4)                 { src = x;  off = e; }
    else if (e < M4 + M1)            { src = Wq; off = e - M4; }
    else if (e < M4 + 2*M1)          { src = Wk; off = e - M4 - M1; }
    else if (e < M4 + 3*M1)          { src = Wv; off = e - M4 - 2*M1; }
    else if (e < M4 + 4*M1)          { src = Wo; off = e - M4 - 3*M1; }
    else if (e < M4 + 4*M1 + 1024)   { src = bq; off = e - M4 - 4*M1; }
    else if (e < M4 + 4*M1 + 2048)   { src = bk; off = e - M4 - 4*M1 - 1024; }
    else if (e < M4 + 4*M1 + 3072)   { src = bv; off = e - M4 - 4*M1 - 2048; }
    else                             { src = bo; off = e - M4 - 4*M1 - 3072; }
    if (f32in) {
        const float4 a = *(const float4*)((const float*)src + off);
        const float4 b = *(const float4*)((const float*)src + off + 4);
        uint4 o;
        o.x = (uint32_t)f2bf(a.x) | ((uint32_t)f2bf(a.y) << 16);
        o.y = (uint32_t)f2bf(a.z) | ((uint32_t)f2bf(a.w) << 16);
        o.z = (uint32_t)f2bf(b.x) | ((uint32_t)f2bf(b.y) << 16);
        o.w = (uint32_t)f2bf(b.z) | ((uint32_t)f2bf(b.w) << 16);
        *(uint4*)(dst + e) = o;
    } else {
        *(uint4*)(dst + e) = *(const uint4*)((const uint16_t*)src + off);
    }
}

// ============================================================
// Fused QKV MFMA GEMM. Q output PRESCALED by 0.125.
// ============================================================
__global__ __launch_bounds__(256)
void gemm_qkv(const uint16_t* __restrict__ xc, const uint16_t* __restrict__ Wqkv,
              const uint16_t* __restrict__ bqkv,
              uint16_t* __restrict__ Qw, uint16_t* __restrict__ Kw,
              uint16_t* __restrict__ Vt)
{
    __shared__ uint16_t As[128 * 32];
    __shared__ uint16_t Bs[128 * 32];
    const int tid = threadIdx.x, bx = blockIdx.x;
    const int lane = tid & 63, wave = tid >> 6;
    const int ln = lane & 15, quad = lane >> 4;
    const int wm = (wave & 1) * 64, wn = (wave >> 1) * 64;

    const uint16_t *Ab, *Bb;
    int bm, bn, vor;
    if (bx < 512) {
        vor = 0; bm = (bx >> 4) * 128; bn = (bx & 15) * 128;
        Ab = xc + (size_t)bm * DM;  Bb = Wqkv + (size_t)bn * DM;
    } else {
        vor = 1; const int b2 = bx - 512; bm = (b2 >> 5) * 128; bn = (b2 & 31) * 128;
        Ab = Wqkv + (size_t)(2048 + bm) * DM;  Bb = xc + (size_t)bn * DM;
    }

    f32x4 acc[4][4];
    #pragma unroll
    for (int i = 0; i < 4; ++i)
        #pragma unroll
        for (int j = 0; j < 4; ++j) acc[i][j] = (f32x4){0.f, 0.f, 0.f, 0.f};

    const int s0 = tid, s1 = 256 + tid;
    const uint16_t* ga0 = Ab + (size_t)(s0 >> 2) * DM + (s0 & 3) * 8;
    const uint16_t* ga1 = Ab + (size_t)(s1 >> 2) * DM + (s1 & 3) * 8;
    const uint16_t* gb0 = Bb + (size_t)(s0 >> 2) * DM + (s0 & 3) * 8;
    const uint16_t* gb1 = Bb + (size_t)(s1 >> 2) * DM + (s1 & 3) * 8;

    for (int k0 = 0; k0 < DM; k0 += 32) {
        __syncthreads();
        gld16(ga0 + k0, &As[s0 * 8]);
        gld16(ga1 + k0, &As[s1 * 8]);
        gld16(gb0 + k0, &Bs[s0 * 8]);
        gld16(gb1 + k0, &Bs[s1 * 8]);
        __syncthreads();

        bf16x8 af[4], bfr[4];
        #pragma unroll
        for (int t = 0; t < 4; ++t) {
            af[t]  = ld_frag(&As[(wm + t * 16 + ln) * 32 + quad * 8]);
            bfr[t] = ld_frag(&Bs[(wn + t * 16 + ln) * 32 + quad * 8]);
        }
        #pragma unroll
        for (int ti = 0; ti < 4; ++ti)
            #pragma unroll
            for (int tj = 0; tj < 4; ++tj)
                acc[ti][tj] = MFMA16(af[ti], bfr[tj], acc[ti][tj]);
    }

    if (!vor) {
        #pragma unroll
        for (int tj = 0; tj < 4; ++tj) {
            const int c = bn + wn + tj * 16 + ln;
            const int mat = c >> 10, h = (c >> 6) & 15, hd = c & 63;
            uint16_t* dstp = mat ? Kw : Qw;
            const float scale = mat ? 1.0f : 0.125f;
            const float bb = bf1(bqkv[c]);
            #pragma unroll
            for (int ti = 0; ti < 4; ++ti)
                #pragma unroll
                for (int r = 0; r < 4; ++r) {
                    const int row = bm + wm + ti * 16 + quad * 4 + r;
                    const int b = row >> 11, s = row & 2047;
                    dstp[(((size_t)b * NH + h) * SEQ + s) * HD + hd] =
                        f2bf((acc[ti][tj][r] + bb) * scale);
                }
        }
    } else {
        #pragma unroll
        for (int ti = 0; ti < 4; ++ti)
            #pragma unroll
            for (int r = 0; r < 4; ++r) {
                const int f = bm + wm + ti * 16 + quad * 4 + r;
                const int h = f >> 6, hd = f & 63;
                const float bb = bf1(bqkv[2048 + f]);
                #pragma unroll
                for (int tj = 0; tj < 4; ++tj) {
                    const int t = bn + wn + tj * 16 + ln;
                    const int b = t >> 11, s = t & 2047;
                    Vt[(((size_t)b * NH + h) * HD + hd) * SEQ + s] = f2bf(acc[ti][tj][r] + bb);
                }
            }
    }
}

// ============================================================
__global__ __launch_bounds__(256)
void gemm_out(const uint16_t* __restrict__ Cw, const uint16_t* __restrict__ Woc,
              const uint16_t* __restrict__ boc, void* __restrict__ out,
              const int* __restrict__ flagp)
{
    __shared__ uint16_t As[128 * 32];
    __shared__ uint16_t Bs[128 * 32];
    const int tid = threadIdx.x, bx = blockIdx.x;
    const int lane = tid & 63, wave = tid >> 6;
    const int ln = lane & 15, quad = lane >> 4;
    const int wm = (wave & 1) * 64, wn = (wave >> 1) * 64;
    const int bm = (bx >> 3) * 128, bn = (bx & 7) * 128;
    const uint16_t* Ab = Cw + (size_t)bm * DM;
    const uint16_t* Bb = Woc + (size_t)bn * DM;

    f32x4 acc[4][4];
    #pragma unroll
    for (int i = 0; i < 4; ++i)
        #pragma unroll
        for (int j = 0; j < 4; ++j) acc[i][j] = (f32x4){0.f, 0.f, 0.f, 0.f};

    const int s0 = tid, s1 = 256 + tid;
    const uint16_t* ga0 = Ab + (size_t)(s0 >> 2) * DM + (s0 & 3) * 8;
    const uint16_t* ga1 = Ab + (size_t)(s1 >> 2) * DM + (s1 & 3) * 8;
    const uint16_t* gb0 = Bb + (size_t)(s0 >> 2) * DM + (s0 & 3) * 8;
    const uint16_t* gb1 = Bb + (size_t)(s1 >> 2) * DM + (s1 & 3) * 8;

    for (int k0 = 0; k0 < DM; k0 += 32) {
        __syncthreads();
        gld16(ga0 + k0, &As[s0 * 8]);
        gld16(ga1 + k0, &As[s1 * 8]);
        gld16(gb0 + k0, &Bs[s0 * 8]);
        gld16(gb1 + k0, &Bs[s1 * 8]);
        __syncthreads();

        bf16x8 af[4], bfr[4];
        #pragma unroll
        for (int t = 0; t < 4; ++t) {
            af[t]  = ld_frag(&As[(wm + t * 16 + ln) * 32 + quad * 8]);
            bfr[t] = ld_frag(&Bs[(wn + t * 16 + ln) * 32 + quad * 8]);
        }
        #pragma unroll
        for (int ti = 0; ti < 4; ++ti)
            #pragma unroll
            for (int tj = 0; tj < 4; ++tj)
                acc[ti][tj] = MFMA16(af[ti], bfr[tj], acc[ti][tj]);
    }

    const bool f32o = (*flagp != 0);
    #pragma unroll
    for (int tj = 0; tj < 4; ++tj) {
        const int c = bn + wn + tj * 16 + ln;
        const float bb = bf1(boc[c]);
        #pragma unroll
        for (int ti = 0; ti < 4; ++ti)
            #pragma unroll
            for (int r = 0; r < 4; ++r) {
                const int row = bm + wm + ti * 16 + quad * 4 + r;
                const float v = acc[ti][tj][r] + bb;
                if (f32o) ((float*)out)[(size_t)row * DM + c] = v;
                else      ((uint16_t*)out)[(size_t)row * DM + c] = f2bf(v);
            }
    }
}

// ============================================================
// Flash-style MFMA attention v7.
// = v6 structure, but 64 q-rows per block (1 m-tile per wave) -> 1024
// blocks. r8 showed 512 blocks = 2 blocks/CU = 2 waves/SIMD -> pure
// latency-bound (Occupancy 11%, MfmaUtil 9%, all pipes idle). LDS is
// unchanged (51.7 KB -> 3 blocks/CU resident), so the grid now supplies
// the occupancy the LDS budget allows: 12 waves/CU.
// ============================================================
__global__ __launch_bounds__(256)
void attn_mfma(const uint16_t* __restrict__ Q, const uint16_t* __restrict__ K,
               const uint16_t* __restrict__ Vt, const void* __restrict__ rel,
               uint16_t* __restrict__ ctx, const int* __restrict__ flagp)
{
    __shared__ alignas(16) uint16_t Ks[128 * 64];    // [key][d], XOR-swizzled
    __shared__ alignas(16) uint16_t Vls[64 * 128];   // [d][key], XOR-swizzled
    __shared__ alignas(16) uint16_t Pl[4][16 * 136]; // per-wave P [q][key], padded
    __shared__ float bias_s[NBUCKET];

    const bool f32in = (*flagp != 0);
    const int tid = threadIdx.x, wave = tid >> 6, lane = tid & 63;
    const int ln = lane & 15, quad = lane >> 4;

    const int blk = blockIdx.x;                         // 1024 blocks
    const int bh = (blk & 7) * 4 + ((blk >> 3) & 3);    // 4 bh per XCD
    const int qt = blk >> 5;                            // 32 q-tiles of 64 rows
    const int b = bh >> 4, h = bh & 15;
    const int q0 = qt * 64;

    for (int i = tid; i < NBUCKET; i += 256)
        bias_s[i] = f32in ? ((const float*)rel)[i * NH + h]
                          : bf1(((const uint16_t*)rel)[i * NH + h]);
    __syncthreads();
    const float bneg = bias_s[0], bpos = bias_s[256];

    // Q B-frags: lane ln = q-row (wave's 16 rows), k = quad*8+j
    const uint16_t* qp = Q + ((size_t)bh * SEQ + q0 + wave * 16 + ln) * HD;
    const bf16x8 qf0 = ld_frag(qp + quad * 8);
    const bf16x8 qf1 = ld_frag(qp + 32 + quad * 8);

    f32x4 o[4];
    float lacc = 0.f;
    #pragma unroll
    for (int dt = 0; dt < 4; ++dt) o[dt] = (f32x4){0.f, 0.f, 0.f, 0.f};

    const uint16_t* Kb  = K  + (size_t)bh * SEQ * HD;
    const uint16_t* Vtb = Vt + (size_t)bh * HD * SEQ;
    const int swz = ln & 7;
    uint16_t* myP = Pl[wave];

    for (int k0 = 0; k0 < SEQ; k0 += 128) {
        __syncthreads();
        #pragma unroll
        for (int it = 0; it < 4; ++it) {   // K tile: 128 rows x 128 B
            const int s = it * 256 + tid;
            const int row = s >> 3, p = s & 7, c = p ^ (row & 7);
            gld16(Kb + (size_t)(k0 + row) * HD + c * 8, &Ks[s * 8]);
        }
        #pragma unroll
        for (int it = 0; it < 4; ++it) {   // V tile: 64 rows x 256 B
            const int s = it * 256 + tid;
            const int row = s >> 4, p = s & 15, c = p ^ (row & 7);
            gld16(Vtb + (size_t)row * SEQ + k0 + c * 8, &Vls[s * 8]);
        }
        __syncthreads();

        // fully-clamped checks for q-tile [q0, q0+63], k-tile [k0, k0+127]
        const int mode = (k0 >= q0 + 192) ? 0 : ((k0 + 256 <= q0) ? 2 : 1);
        const float bcst = ((mode == 0) ? bneg : bpos) - 8.0f;

        // ---- S^T = K·Q^T; exp; P -> LDS (one b64 per 16-key tile) ----
        #pragma unroll
        for (int nt = 0; nt < 8; ++nt) {
            const int krow = (nt * 16 + ln) * 64;
            const bf16x8 kf0 = ld_frag(&Ks[krow + ((0 + quad) ^ swz) * 8]);
            const bf16x8 kf1 = ld_frag(&Ks[krow + ((4 + quad) ^ swz) * 8]);
            f32x4 s4 = (f32x4){0.f, 0.f, 0.f, 0.f};
            s4 = MFMA16(kf0, qf0, s4);   // A=K(rows=keys), B=Q(cols=q)
            s4 = MFMA16(kf1, qf1, s4);
            uint32_t pb[4];
            #pragma unroll
            for (int r = 0; r < 4; ++r) {
                float sv;
                if (mode != 1) {
                    sv = s4[r] + bcst;
                } else {
                    const int kk = k0 + nt * 16 + quad * 4 + r;
                    const int qq = q0 + wave * 16 + ln;
                    int dd = qq - kk;
                    dd = min(128, max(-128, dd)) + 128;
                    sv = s4[r] + bias_s[dd] - 8.0f;
                }
                pb[r] = __float_as_uint(__expf(sv)) & 0xffff0000u;
                lacc += __uint_as_float(pb[r]);   // l matches bf16 P
            }
            const uint2 dw = {__builtin_amdgcn_perm(pb[1], pb[0], 0x07060302u),
                              __builtin_amdgcn_perm(pb[3], pb[2], 0x07060302u)};
            *(uint2*)&myP[ln * 136 + nt * 16 + quad * 4] = dw;
        }
        // ---- PV ----
        bf16x8 pf[4];
        #pragma unroll
        for (int kc = 0; kc < 4; ++kc)
            pf[kc] = ld_frag(&myP[ln * 136 + kc * 32 + quad * 8]);
        #pragma unroll
        for (int dt = 0; dt < 4; ++dt) {
            const int vrow = (dt * 16 + ln) * 128;
            #pragma unroll
            for (int kc = 0; kc < 4; ++kc) {
                const bf16x8 vf = ld_frag(&Vls[vrow + ((kc * 4 + quad) ^ swz) * 8]);
                o[dt] = MFMA16(pf[kc], vf, o[dt]);
            }
        }
    }

    // ---- epilogue: reduce l over quads, redistribute, divide, store ----
    float lr = lacc;
    lr += __shfl_xor(lr, 16);
    lr += __shfl_xor(lr, 32);
    const float linv = 1.0f / lr;      // valid for q-row = ln
    #pragma unroll
    for (int r = 0; r < 4; ++r) {
        const float inv_r = __shfl(linv, quad * 4 + r);  // l for q=quad*4+r
        const int qq = q0 + wave * 16 + quad * 4 + r;
        #pragma unroll
        for (int dt = 0; dt < 4; ++dt) {
            const float v = o[dt][r] * inv_r;
            ctx[(((size_t)b * SEQ + qq) * NH + h) * HD + dt * 16 + ln] = f2bf(v);
        }
    }
}

// ============================================================
extern "C" void kernel_launch(void* const* d_in, const int* in_sizes, int n_in,
                              void* d_out, int out_size, void* d_ws, size_t ws_size,
                              hipStream_t stream)
{
    const void* x   = d_in[0];
    const void* Wq  = d_in[1];
    const void* bq  = d_in[2];
    const void* Wk  = d_in[3];
    const void* bk  = d_in[4];
    const void* Wv  = d_in[5];
    const void* bv  = d_in[6];
    const void* Wo  = d_in[7];
    const void* bo  = d_in[8];
    const void* rel = d_in[9];

    const size_t M4 = 4194304, M1 = 1048576;
    uint16_t* ws16 = (uint16_t*)d_ws;
    uint16_t* xc   = ws16;                    // 4M; reused as Cw after QKV GEMM
    uint16_t* Wqkv = ws16 + M4;               // 3M  [Wq;Wk;Wv]
    uint16_t* Woc  = ws16 + M4 + 3 * M1;      // 1M
    uint16_t* bqkv = ws16 + M4 + 4 * M1;      // 3072 [bq;bk;bv]
    uint16_t* boc  = bqkv + 3072;             // 1024
    uint16_t* Qw   = ws16 + M4 + 4 * M1 + 8192;
    uint16_t* Kw   = Qw + M4;
    uint16_t* Vt   = Kw + M4;
    int* flag = (int*)(Vt + M4);
    uint16_t* Cw = xc;   // overlay: xc dead after gemm_qkv

    sniff_kernel<<<1, 64, 0, stream>>>((const uint16_t*)x, flag);
    convert_kernel<<<4098, 256, 0, stream>>>(x, Wq, Wk, Wv, Wo, bq, bk, bv, bo,
                                             ws16, flag);
    gemm_qkv<<<768, 256, 0, stream>>>(xc, Wqkv, bqkv, Qw, Kw, Vt);
    attn_mfma<<<1024, 256, 0, stream>>>(Qw, Kw, Vt, rel, Cw, flag);
    gemm_out<<<256, 256, 0, stream>>>(Cw, Woc, boc, d_out, flag);
}

// Round 10
// 239.508 us; speedup vs baseline: 2.1430x; 1.0754x over previous
//
#include <hip/hip_runtime.h>
#include <hip/hip_bf16.h>
#include <cstdint>
#include <cstddef>

#define DEVI __device__ __forceinline__

static constexpr int SEQ = 2048;
static constexpr int DM  = 1024;
static constexpr int NH  = 16;
static constexpr int HD  = 64;
static constexpr int NTOK = 2 * SEQ;
static constexpr int NBUCKET = 257;
static constexpr float LOG2E = 1.44269504088896f;

typedef __attribute__((ext_vector_type(8))) short bf16x8;
typedef __attribute__((ext_vector_type(4))) float f32x4;
#define MFMA16(a, b, c) __builtin_amdgcn_mfma_f32_16x16x32_bf16((a), (b), (c), 0, 0, 0)

DEVI float bf1(uint16_t u)  { return __uint_as_float(((uint32_t)u) << 16); }
DEVI uint16_t f2bf(float f) {
    uint32_t x = __float_as_uint(f);
    x += 0x7fffu + ((x >> 16) & 1u);   // RTNE
    return (uint16_t)(x >> 16);
}
DEVI bf16x8 ld_frag(const uint16_t* p) {
    union { uint4 u; bf16x8 f; } c;
    c.u = *(const uint4*)p;
    return c.f;
}
DEVI void gld16(const uint16_t* g, uint16_t* l) {
    __builtin_amdgcn_global_load_lds(
        (const __attribute__((address_space(1))) uint32_t*)g,
        (__attribute__((address_space(3))) uint32_t*)l, 16, 0, 0);
}

// ============================================================
__global__ void sniff_kernel(const uint16_t* __restrict__ x, int* __restrict__ flag)
{
    int bad = 0;
    for (int i = threadIdx.x; i < 512; i += 64) {
        const float v = bf1(x[i]);
        if (!(fabsf(v) < 64.0f)) bad = 1;
    }
    const unsigned long long m = __ballot(bad);
    if (threadIdx.x == 0) *flag = (m != 0ull) ? 1 : 0;
}

// ============================================================
__global__ __launch_bounds__(256)
void convert_kernel(const void* __restrict__ x, const void* __restrict__ Wq,
                    const void* __restrict__ Wk, const void* __restrict__ Wv,
                    const void* __restrict__ Wo, const void* __restrict__ bq,
                    const void* __restrict__ bk, const void* __restrict__ bv,
                    const void* __restrict__ bo, uint16_t* __restrict__ dst,
                    const int* __restrict__ flagp)
{
    const bool f32in = (*flagp != 0);
    const size_t M4 = 4194304, M1 = 1048576;
    const size_t e = ((size_t)blockIdx.x * 256 + threadIdx.x) * 8;
    const void* src; size_t off;
    if      (e < M4)                 { src = x;  off = e; }
    else if (e < M4 + M1)            { src = Wq; off = e - M4; }
    else if (e < M4 + 2*M1)          { src = Wk; off = e - M4 - M1; }
    else if (e < M4 + 3*M1)          { src = Wv; off = e - M4 - 2*M1; }
    else if (e < M4 + 4*M1)          { src = Wo; off = e - M4 - 3*M1; }
    else if (e < M4 + 4*M1 + 1024)   { src = bq; off = e - M4 - 4*M1; }
    else if (e < M4 + 4*M1 + 2048)   { src = bk; off = e - M4 - 4*M1 - 1024; }
    else if (e < M4 + 4*M1 + 3072)   { src = bv; off = e - M4 - 4*M1 - 2048; }
    else                             { src = bo; off = e - M4 - 4*M1 - 3072; }
    if (f32in) {
        const float4 a = *(const float4*)((const float*)src + off);
        const float4 b = *(const float4*)((const float*)src + off + 4);
        uint4 o;
        o.x = (uint32_t)f2bf(a.x) | ((uint32_t)f2bf(a.y) << 16);
        o.y = (uint32_t)f2bf(a.z) | ((uint32_t)f2bf(a.w) << 16);
        o.z = (uint32_t)f2bf(b.x) | ((uint32_t)f2bf(b.y) << 16);
        o.w = (uint32_t)f2bf(b.z) | ((uint32_t)f2bf(b.w) << 16);
        *(uint4*)(dst + e) = o;
    } else {
        *(uint4*)(dst + e) = *(const uint4*)((const uint16_t*)src + off);
    }
}

// ============================================================
// Fused QKV MFMA GEMM. Q output PRESCALED by 0.125*log2(e) so attention
// can use exp2 directly (saves one v_mul per score).
// ============================================================
__global__ __launch_bounds__(256)
void gemm_qkv(const uint16_t* __restrict__ xc, const uint16_t* __restrict__ Wqkv,
              const uint16_t* __restrict__ bqkv,
              uint16_t* __restrict__ Qw, uint16_t* __restrict__ Kw,
              uint16_t* __restrict__ Vt)
{
    __shared__ uint16_t As[128 * 32];
    __shared__ uint16_t Bs[128 * 32];
    const int tid = threadIdx.x, bx = blockIdx.x;
    const int lane = tid & 63, wave = tid >> 6;
    const int ln = lane & 15, quad = lane >> 4;
    const int wm = (wave & 1) * 64, wn = (wave >> 1) * 64;

    const uint16_t *Ab, *Bb;
    int bm, bn, vor;
    if (bx < 512) {
        vor = 0; bm = (bx >> 4) * 128; bn = (bx & 15) * 128;
        Ab = xc + (size_t)bm * DM;  Bb = Wqkv + (size_t)bn * DM;
    } else {
        vor = 1; const int b2 = bx - 512; bm = (b2 >> 5) * 128; bn = (b2 & 31) * 128;
        Ab = Wqkv + (size_t)(2048 + bm) * DM;  Bb = xc + (size_t)bn * DM;
    }

    f32x4 acc[4][4];
    #pragma unroll
    for (int i = 0; i < 4; ++i)
        #pragma unroll
        for (int j = 0; j < 4; ++j) acc[i][j] = (f32x4){0.f, 0.f, 0.f, 0.f};

    const int s0 = tid, s1 = 256 + tid;
    const uint16_t* ga0 = Ab + (size_t)(s0 >> 2) * DM + (s0 & 3) * 8;
    const uint16_t* ga1 = Ab + (size_t)(s1 >> 2) * DM + (s1 & 3) * 8;
    const uint16_t* gb0 = Bb + (size_t)(s0 >> 2) * DM + (s0 & 3) * 8;
    const uint16_t* gb1 = Bb + (size_t)(s1 >> 2) * DM + (s1 & 3) * 8;

    for (int k0 = 0; k0 < DM; k0 += 32) {
        __syncthreads();
        gld16(ga0 + k0, &As[s0 * 8]);
        gld16(ga1 + k0, &As[s1 * 8]);
        gld16(gb0 + k0, &Bs[s0 * 8]);
        gld16(gb1 + k0, &Bs[s1 * 8]);
        __syncthreads();

        bf16x8 af[4], bfr[4];
        #pragma unroll
        for (int t = 0; t < 4; ++t) {
            af[t]  = ld_frag(&As[(wm + t * 16 + ln) * 32 + quad * 8]);
            bfr[t] = ld_frag(&Bs[(wn + t * 16 + ln) * 32 + quad * 8]);
        }
        #pragma unroll
        for (int ti = 0; ti < 4; ++ti)
            #pragma unroll
            for (int tj = 0; tj < 4; ++tj)
                acc[ti][tj] = MFMA16(af[ti], bfr[tj], acc[ti][tj]);
    }

    if (!vor) {
        #pragma unroll
        for (int tj = 0; tj < 4; ++tj) {
            const int c = bn + wn + tj * 16 + ln;
            const int mat = c >> 10, h = (c >> 6) & 15, hd = c & 63;
            uint16_t* dstp = mat ? Kw : Qw;
            const float scale = mat ? 1.0f : (0.125f * LOG2E);
            const float bb = bf1(bqkv[c]);
            #pragma unroll
            for (int ti = 0; ti < 4; ++ti)
                #pragma unroll
                for (int r = 0; r < 4; ++r) {
                    const int row = bm + wm + ti * 16 + quad * 4 + r;
                    const int b = row >> 11, s = row & 2047;
                    dstp[(((size_t)b * NH + h) * SEQ + s) * HD + hd] =
                        f2bf((acc[ti][tj][r] + bb) * scale);
                }
        }
    } else {
        #pragma unroll
        for (int ti = 0; ti < 4; ++ti)
            #pragma unroll
            for (int r = 0; r < 4; ++r) {
                const int f = bm + wm + ti * 16 + quad * 4 + r;
                const int h = f >> 6, hd = f & 63;
                const float bb = bf1(bqkv[2048 + f]);
                #pragma unroll
                for (int tj = 0; tj < 4; ++tj) {
                    const int t = bn + wn + tj * 16 + ln;
                    const int b = t >> 11, s = t & 2047;
                    Vt[(((size_t)b * NH + h) * HD + hd) * SEQ + s] = f2bf(acc[ti][tj][r] + bb);
                }
            }
    }
}

// ============================================================
// Output projection: out = Cw · Woc^T + bo. 128x64 tiles -> 512 blocks
// (2/CU; the old 128x128/256-block config was 1 block/CU, under-occupied).
// ============================================================
__global__ __launch_bounds__(256)
void gemm_out(const uint16_t* __restrict__ Cw, const uint16_t* __restrict__ Woc,
              const uint16_t* __restrict__ boc, void* __restrict__ out,
              const int* __restrict__ flagp)
{
    __shared__ uint16_t As[128 * 32];
    __shared__ uint16_t Bs[64 * 32];
    const int tid = threadIdx.x, bx = blockIdx.x;
    const int lane = tid & 63, wave = tid >> 6;
    const int ln = lane & 15, quad = lane >> 4;
    const int wm = (wave & 1) * 64, wn = (wave >> 1) * 32;
    const int bm = (bx >> 4) * 128, bn = (bx & 15) * 64;
    const uint16_t* Ab = Cw + (size_t)bm * DM;
    const uint16_t* Bb = Woc + (size_t)bn * DM;

    f32x4 acc[4][2];
    #pragma unroll
    for (int i = 0; i < 4; ++i)
        #pragma unroll
        for (int j = 0; j < 2; ++j) acc[i][j] = (f32x4){0.f, 0.f, 0.f, 0.f};

    const int s0 = tid, s1 = 256 + tid;
    const uint16_t* ga0 = Ab + (size_t)(s0 >> 2) * DM + (s0 & 3) * 8;
    const uint16_t* ga1 = Ab + (size_t)(s1 >> 2) * DM + (s1 & 3) * 8;
    const uint16_t* gb0 = Bb + (size_t)(s0 >> 2) * DM + (s0 & 3) * 8;

    for (int k0 = 0; k0 < DM; k0 += 32) {
        __syncthreads();
        gld16(ga0 + k0, &As[s0 * 8]);
        gld16(ga1 + k0, &As[s1 * 8]);
        gld16(gb0 + k0, &Bs[s0 * 8]);
        __syncthreads();

        bf16x8 af[4], bfr[2];
        #pragma unroll
        for (int t = 0; t < 4; ++t)
            af[t] = ld_frag(&As[(wm + t * 16 + ln) * 32 + quad * 8]);
        #pragma unroll
        for (int t = 0; t < 2; ++t)
            bfr[t] = ld_frag(&Bs[(wn + t * 16 + ln) * 32 + quad * 8]);
        #pragma unroll
        for (int ti = 0; ti < 4; ++ti)
            #pragma unroll
            for (int tj = 0; tj < 2; ++tj)
                acc[ti][tj] = MFMA16(af[ti], bfr[tj], acc[ti][tj]);
    }

    const bool f32o = (*flagp != 0);
    #pragma unroll
    for (int tj = 0; tj < 2; ++tj) {
        const int c = bn + wn + tj * 16 + ln;
        const float bb = bf1(boc[c]);
        #pragma unroll
        for (int ti = 0; ti < 4; ++ti)
            #pragma unroll
            for (int r = 0; r < 4; ++r) {
                const int row = bm + wm + ti * 16 + quad * 4 + r;
                const float v = acc[ti][tj][r] + bb;
                if (f32o) ((float*)out)[(size_t)row * DM + c] = v;
                else      ((uint16_t*)out)[(size_t)row * DM + c] = f2bf(v);
            }
    }
}

// ============================================================
// Flash-style MFMA attention v8.
// = v7 structure with K-tile 64 (32 iters) -> LDS 25.2 KB. With 1024
// blocks, all 4 blocks/CU are RESIDENT SIMULTANEOUSLY (16 waves/CU):
// r9's 3-resident + straggler-phase packing (avg occupancy 24%) becomes
// single-phase full packing. Ks/Vls/Pl all XOR-swizzled (b128 reads at
// the 8-slot floor, b64 P-writes at the 2-way floor).
// exp2-folded softmax: Q prescaled by 0.125*log2e, bias table *log2e.
// ============================================================
__global__ __launch_bounds__(256)
void attn_mfma(const uint16_t* __restrict__ Q, const uint16_t* __restrict__ K,
               const uint16_t* __restrict__ Vt, const void* __restrict__ rel,
               uint16_t* __restrict__ ctx, const int* __restrict__ flagp)
{
    __shared__ alignas(16) uint16_t Ks[64 * 64];     // [key][d], swizzled, 8 KB
    __shared__ alignas(16) uint16_t Vls[64 * 64];    // [d][key], swizzled, 8 KB
    __shared__ alignas(16) uint16_t Pl[4][16 * 64];  // per-wave P, swizzled, 8 KB
    __shared__ float bias_s[NBUCKET];                // pre-multiplied by log2e

    const bool f32in = (*flagp != 0);
    const int tid = threadIdx.x, wave = tid >> 6, lane = tid & 63;
    const int ln = lane & 15, quad = lane >> 4;

    const int blk = blockIdx.x;                         // 1024 blocks
    const int bh = (blk & 7) * 4 + ((blk >> 3) & 3);    // 4 bh per XCD
    const int qt = blk >> 5;                            // 32 q-tiles of 64 rows
    const int b = bh >> 4, h = bh & 15;
    const int q0 = qt * 64;

    for (int i = tid; i < NBUCKET; i += 256) {
        const float bv = f32in ? ((const float*)rel)[i * NH + h]
                               : bf1(((const uint16_t*)rel)[i * NH + h]);
        bias_s[i] = bv * LOG2E;
    }
    __syncthreads();
    const float bneg = bias_s[0], bpos = bias_s[256];
    const float C8 = 8.0f * LOG2E;   // fixed-max shift (in exp2 domain)

    // Q B-frags: lane ln = q-row (wave's 16 rows), k = quad*8+j
    const uint16_t* qp = Q + ((size_t)bh * SEQ + q0 + wave * 16 + ln) * HD;
    const bf16x8 qf0 = ld_frag(qp + quad * 8);
    const bf16x8 qf1 = ld_frag(qp + 32 + quad * 8);

    f32x4 o[4];
    float lacc = 0.f;
    #pragma unroll
    for (int dt = 0; dt < 4; ++dt) o[dt] = (f32x4){0.f, 0.f, 0.f, 0.f};

    const uint16_t* Kb  = K  + (size_t)bh * SEQ * HD;
    const uint16_t* Vtb = Vt + (size_t)bh * HD * SEQ;
    const int swz = ln & 7;
    uint16_t* myP = Pl[wave];

    for (int k0 = 0; k0 < SEQ; k0 += 64) {
        __syncthreads();
        #pragma unroll
        for (int it = 0; it < 2; ++it) {   // K tile: 64 rows x 128 B
            const int s = it * 256 + tid;
            const int row = s >> 3, p = s & 7, c = p ^ (row & 7);
            gld16(Kb + (size_t)(k0 + row) * HD + c * 8, &Ks[s * 8]);
        }
        #pragma unroll
        for (int it = 0; it < 2; ++it) {   // V tile: 64 rows x 128 B
            const int s = it * 256 + tid;
            const int row = s >> 3, p = s & 7, c = p ^ (row & 7);
            gld16(Vtb + (size_t)row * SEQ + k0 + c * 8, &Vls[s * 8]);
        }
        __syncthreads();

        // q-tile [q0, q0+63], k-tile [k0, k0+63]
        const int mode = (k0 >= q0 + 192) ? 0 : ((k0 + 192 <= q0) ? 2 : 1);
        const float bcst = ((mode == 0) ? bneg : bpos) - C8;

        // ---- S^T = K·Q^T; exp2; P -> LDS (one b64 per 16-key tile) ----
        #pragma unroll
        for (int nt = 0; nt < 4; ++nt) {
            const int krow = (nt * 16 + ln) * 64;
            const bf16x8 kf0 = ld_frag(&Ks[krow + ((0 + quad) ^ swz) * 8]);
            const bf16x8 kf1 = ld_frag(&Ks[krow + ((4 + quad) ^ swz) * 8]);
            f32x4 s4 = (f32x4){0.f, 0.f, 0.f, 0.f};
            s4 = MFMA16(kf0, qf0, s4);   // A=K(rows=keys), B=Q(cols=q)
            s4 = MFMA16(kf1, qf1, s4);
            uint32_t pb[4];
            #pragma unroll
            for (int r = 0; r < 4; ++r) {
                float sv;
                if (mode != 1) {
                    sv = s4[r] + bcst;
                } else {
                    const int kk = k0 + nt * 16 + quad * 4 + r;
                    const int qq = q0 + wave * 16 + ln;
                    int dd = qq - kk;
                    dd = min(128, max(-128, dd)) + 128;
                    sv = s4[r] + bias_s[dd] - C8;
                }
                pb[r] = __float_as_uint(exp2f(sv)) & 0xffff0000u;
                lacc += __uint_as_float(pb[r]);   // l matches bf16 P
            }
            const uint2 dw = {__builtin_amdgcn_perm(pb[1], pb[0], 0x07060302u),
                              __builtin_amdgcn_perm(pb[3], pb[2], 0x07060302u)};
            const int cb = (2 * nt + (quad >> 1)) ^ swz;
            *(uint2*)&myP[ln * 64 + cb * 8 + (quad & 1) * 4] = dw;
        }
        // ---- PV ----
        bf16x8 pf[2];
        #pragma unroll
        for (int kc = 0; kc < 2; ++kc)
            pf[kc] = ld_frag(&myP[ln * 64 + ((kc * 4 + quad) ^ swz) * 8]);
        #pragma unroll
        for (int dt = 0; dt < 4; ++dt) {
            const int vrow = (dt * 16 + ln) * 64;
            #pragma unroll
            for (int kc = 0; kc < 2; ++kc) {
                const bf16x8 vf = ld_frag(&Vls[vrow + ((kc * 4 + quad) ^ swz) * 8]);
                o[dt] = MFMA16(pf[kc], vf, o[dt]);
            }
        }
    }

    // ---- epilogue: reduce l over quads, redistribute, divide, store ----
    float lr = lacc;
    lr += __shfl_xor(lr, 16);
    lr += __shfl_xor(lr, 32);
    const float linv = 1.0f / lr;      // valid for q-row = ln
    #pragma unroll
    for (int r = 0; r < 4; ++r) {
        const float inv_r = __shfl(linv, quad * 4 + r);  // l for q=quad*4+r
        const int qq = q0 + wave * 16 + quad * 4 + r;
        #pragma unroll
        for (int dt = 0; dt < 4; ++dt) {
            const float v = o[dt][r] * inv_r;
            ctx[(((size_t)b * SEQ + qq) * NH + h) * HD + dt * 16 + ln] = f2bf(v);
        }
    }
}

// ============================================================
extern "C" void kernel_launch(void* const* d_in, const int* in_sizes, int n_in,
                              void* d_out, int out_size, void* d_ws, size_t ws_size,
                              hipStream_t stream)
{
    const void* x   = d_in[0];
    const void* Wq  = d_in[1];
    const void* bq  = d_in[2];
    const void* Wk  = d_in[3];
    const void* bk  = d_in[4];
    const void* Wv  = d_in[5];
    const void* bv  = d_in[6];
    const void* Wo  = d_in[7];
    const void* bo  = d_in[8];
    const void* rel = d_in[9];

    const size_t M4 = 4194304, M1 = 1048576;
    uint16_t* ws16 = (uint16_t*)d_ws;
    uint16_t* xc   = ws16;                    // 4M; reused as Cw after QKV GEMM
    uint16_t* Wqkv = ws16 + M4;               // 3M  [Wq;Wk;Wv]
    uint16_t* Woc  = ws16 + M4 + 3 * M1;      // 1M
    uint16_t* bqkv = ws16 + M4 + 4 * M1;      // 3072 [bq;bk;bv]
    uint16_t* boc  = bqkv + 3072;             // 1024
    uint16_t* Qw   = ws16 + M4 + 4 * M1 + 8192;
    uint16_t* Kw   = Qw + M4;
    uint16_t* Vt   = Kw + M4;
    int* flag = (int*)(Vt + M4);
    uint16_t* Cw = xc;   // overlay: xc dead after gemm_qkv

    sniff_kernel<<<1, 64, 0, stream>>>((const uint16_t*)x, flag);
    convert_kernel<<<4098, 256, 0, stream>>>(x, Wq, Wk, Wv, Wo, bq, bk, bv, bo,
                                             ws16, flag);
    gemm_qkv<<<768, 256, 0, stream>>>(xc, Wqkv, bqkv, Qw, Kw, Vt);
    attn_mfma<<<1024, 256, 0, stream>>>(Qw, Kw, Vt, rel, Cw, flag);
    gemm_out<<<512, 256, 0, stream>>>(Cw, Woc, boc, d_out, flag);
}